// Round 10
// baseline (431.134 us; speedup 1.0000x reference)
//
#include <hip/hip_runtime.h>
#include <hip/hip_bf16.h>
#include <hip/hip_fp16.h>
#include <stdint.h>

#define TPB 256
#define EPSF 1e-5f

using i32x4 = __attribute__((ext_vector_type(4))) int;

// ---------------- helpers ----------------

__device__ __forceinline__ void gload16(const void* g, void* l) {
    __builtin_amdgcn_global_load_lds(
        (__attribute__((address_space(1))) void*)g,
        (__attribute__((address_space(3))) void*)l,
        16, 0, 0);
}

__device__ __forceinline__ float wave_reduce_sum(float v) {
#pragma unroll
    for (int off = 32; off > 0; off >>= 1) v += __shfl_down(v, off, 64);
    return v;
}

__device__ __forceinline__ float wave_reduce_max(float v) {
#pragma unroll
    for (int off = 32; off > 0; off >>= 1) v = fmaxf(v, __shfl_down(v, off, 64));
    return v;
}

__device__ __forceinline__ int q8(float f, float scale, float lo, float hi) {
    return (int)fminf(fmaxf(rintf(f * scale), lo), hi);
}

// fast GELU: x * sigmoid(2*u), u = sqrt(2/pi)*(x + 0.044715 x^3)
__device__ __forceinline__ float gelu_fast(float x) {
    float x2 = x * x;
    float u = x * (0.7978845608f + 0.0356774081f * x2);
    float e = exp2f(u * -2.8853900817779268f);   // exp(-2u)
    return x * __builtin_amdgcn_rcpf(1.0f + e);
}

// ---------------- scale reduction (deterministic two-pass) ----------------

__global__ void abssum2(const float* __restrict__ w1, const float* __restrict__ w2,
                        int n4, float* __restrict__ part) {
    const bool second = blockIdx.x >= 2048;
    const float4* w4 = (const float4*)(second ? w2 : w1);
    const int b = blockIdx.x & 2047;
    float acc = 0.f;
    for (int i = b * TPB + threadIdx.x; i < n4; i += 2048 * TPB) {
        float4 v = w4[i];
        acc += fabsf(v.x) + fabsf(v.y) + fabsf(v.z) + fabsf(v.w);
    }
    acc = wave_reduce_sum(acc);
    __shared__ float sh[4];
    if ((threadIdx.x & 63) == 0) sh[threadIdx.x >> 6] = acc;
    __syncthreads();
    if (threadIdx.x == 0) part[blockIdx.x] = sh[0] + sh[1] + sh[2] + sh[3];
}

__global__ void finalize_scales(const float* __restrict__ part,
                                float* __restrict__ scales, float inv_n) {
    float a = 0.f, b = 0.f;
    for (int i = threadIdx.x; i < 2048; i += TPB) { a += part[i]; b += part[i + 2048]; }
    a = wave_reduce_sum(a);
    b = wave_reduce_sum(b);
    __shared__ float sa[4], sb[4];
    if ((threadIdx.x & 63) == 0) { sa[threadIdx.x >> 6] = a; sb[threadIdx.x >> 6] = b; }
    __syncthreads();
    if (threadIdx.x == 0) {
        scales[0] = fmaxf((sa[0] + sa[1] + sa[2] + sa[3]) * inv_n, EPSF);
        scales[1] = fmaxf((sb[0] + sb[1] + sb[2] + sb[3]) * inv_n, EPSF);
    }
}

// ---------------- weight ternarization -> int8 ----------------

__global__ void quant_w_i8(const float* __restrict__ w,
                           signed char* __restrict__ wq,
                           const float* __restrict__ scales, int sidx, int n4) {
    const float inv = 1.0f / scales[sidx];
    const float4* w4 = (const float4*)w;
    unsigned* oq = (unsigned*)wq;
    for (int i = blockIdx.x * TPB + threadIdx.x; i < n4; i += gridDim.x * TPB) {
        float4 v = w4[i];
        unsigned p = ((unsigned)(q8(v.x, inv, -1.f, 1.f) & 0xff)) |
                     ((unsigned)(q8(v.y, inv, -1.f, 1.f) & 0xff) << 8) |
                     ((unsigned)(q8(v.z, inv, -1.f, 1.f) & 0xff) << 16) |
                     ((unsigned)(q8(v.w, inv, -1.f, 1.f) & 0xff) << 24);
        oq[i] = p;
    }
}

// ---------------- per-row activation quant: fp32 -> int8 ----------------

template <int NF4>
__global__ void quant_x_i8(const float* __restrict__ in,
                           signed char* __restrict__ outq,
                           float* __restrict__ dq, int cols) {
    const long long row = blockIdx.x;
    const float4* r4 = (const float4*)(in + row * (long long)cols);
    float4 v[NF4];
    float mx = 0.f;
#pragma unroll
    for (int j = 0; j < NF4; ++j) {
        v[j] = r4[threadIdx.x + TPB * j];
        mx = fmaxf(mx, fmaxf(fmaxf(fabsf(v[j].x), fabsf(v[j].y)),
                             fmaxf(fabsf(v[j].z), fabsf(v[j].w))));
    }
    mx = wave_reduce_max(mx);
    __shared__ float sh[4];
    __shared__ float res;
    if ((threadIdx.x & 63) == 0) sh[threadIdx.x >> 6] = mx;
    __syncthreads();
    if (threadIdx.x == 0) res = fmaxf(fmaxf(sh[0], sh[1]), fmaxf(sh[2], sh[3]));
    __syncthreads();
    const float clipped = fmaxf(res, EPSF);
    const float scale = 127.f / clipped;
    if (threadIdx.x == 0) dq[row] = clipped / 127.f;
    unsigned* oq = (unsigned*)(outq + row * (long long)cols);
#pragma unroll
    for (int j = 0; j < NF4; ++j) {
        unsigned p = ((unsigned)(q8(v[j].x, scale, -128.f, 127.f) & 0xff)) |
                     ((unsigned)(q8(v[j].y, scale, -128.f, 127.f) & 0xff) << 8) |
                     ((unsigned)(q8(v[j].z, scale, -128.f, 127.f) & 0xff) << 16) |
                     ((unsigned)(q8(v[j].w, scale, -128.f, 127.f) & 0xff) << 24);
        oq[threadIdx.x + TPB * j] = p;
    }
}

// ---------------- per-row quant: fp16 -> int8 (for h) ----------------

template <int NJ>
__global__ void quant_h_i8(const unsigned short* __restrict__ h,
                           signed char* __restrict__ outq,
                           float* __restrict__ dq, int cols) {
    const long long row = blockIdx.x;
    const unsigned short* rp = h + row * (long long)cols;
    uint4 v[NJ];
    float mx = 0.f;
#pragma unroll
    for (int j = 0; j < NJ; ++j) {
        v[j] = *(const uint4*)(rp + (threadIdx.x + TPB * j) * 8);
        const unsigned* u = (const unsigned*)&v[j];
#pragma unroll
        for (int e = 0; e < 4; ++e) {
            float2 f2 = __half22float2(*(const __half2*)&u[e]);
            mx = fmaxf(mx, fmaxf(fabsf(f2.x), fabsf(f2.y)));
        }
    }
    mx = wave_reduce_max(mx);
    __shared__ float sh[4];
    __shared__ float res;
    if ((threadIdx.x & 63) == 0) sh[threadIdx.x >> 6] = mx;
    __syncthreads();
    if (threadIdx.x == 0) res = fmaxf(fmaxf(sh[0], sh[1]), fmaxf(sh[2], sh[3]));
    __syncthreads();
    const float clipped = fmaxf(res, EPSF);
    const float scale = 127.f / clipped;
    if (threadIdx.x == 0) dq[row] = clipped / 127.f;
    uint2* oq = (uint2*)(outq + row * (long long)cols);
#pragma unroll
    for (int j = 0; j < NJ; ++j) {
        const unsigned* u = (const unsigned*)&v[j];
        unsigned o[2] = {0, 0};
#pragma unroll
        for (int e = 0; e < 4; ++e) {
            float2 f2 = __half22float2(*(const __half2*)&u[e]);
            unsigned b0 = (unsigned)(q8(f2.x, scale, -128.f, 127.f) & 0xff);
            unsigned b1 = (unsigned)(q8(f2.y, scale, -128.f, 127.f) & 0xff);
            o[e >> 1] |= (b0 | (b1 << 8)) << ((e & 1) * 16);
        }
        oq[threadIdx.x + TPB * j] = *(uint2*)o;
    }
}

// ---------------- GEMM pieces (4-wave blocks, 256 threads) ----------------

// stage N32*32 rows x 128B into LDS (linear dest, pre-swizzled global col)
template <int N32>
__device__ __forceinline__ void stageN(const char* Xb, long long rowB, int prow,
                                       int tk, char* dst, int tid, int cbs) {
    const long long gc = (long long)tk * 128 + cbs;
    const int r = tid >> 3;
#pragma unroll
    for (int j = 0; j < N32; ++j)
        gload16(Xb + (long long)(prow + j * 32 + r) * rowB + gc,
                dst + j * 4096 + tid * 16);
}

#define QUAD(MB, NB)                                                            \
    _Pragma("unroll") for (int mi = 0; mi < 4; ++mi)                            \
    _Pragma("unroll") for (int ni = 0; ni < 2; ++ni)                            \
    _Pragma("unroll") for (int ks = 0; ks < 2; ++ks)                            \
        acc[(MB)*4 + mi][(NB)*2 + ni] = __builtin_amdgcn_mfma_i32_16x16x64_i8(  \
            aq[mi][ks], bq[(NB)*2 + ni][ks], acc[(MB)*4 + mi][(NB)*2 + ni], 0, 0, 0);

#define READ_A(BUF, base_mi)                                                    \
    _Pragma("unroll") for (int mi = 0; mi < 4; ++mi) {                          \
        const char* p = (BUF) + aoff + ((mi + (base_mi)) * 16 + l15) * 128;     \
        aq[mi][0] = *(const i32x4*)(p + acb0);                                  \
        aq[mi][1] = *(const i32x4*)(p + acb1);                                  \
    }
#define READ_B(BUF)                                                             \
    _Pragma("unroll") for (int ni = 0; ni < 4; ++ni) {                          \
        const char* p = (BUF) + boff + (ni * 16 + l15) * 128;                   \
        bq[ni][0] = *(const i32x4*)(p + acb0);                                  \
        bq[ni][1] = *(const i32x4*)(p + acb1);                                  \
    }

#define LGKM0 do { asm volatile("s_waitcnt lgkmcnt(0)" ::: "memory");           \
                   __builtin_amdgcn_sched_barrier(0); } while (0)

#define BUFSZ 49152

// 256x128 tile, 4 waves (2Mx2N), BK=128 i8, double-buffered 96KB LDS,
// 2 blocks/CU -> sibling-block LDS/MFMA overlap. R4-pinned 4-phase ledger:
// stages A1@P0->nxt, B0@P1->cur, B1@P2->cur, A0@P3->cur; vmcnt(8).
// OUT=1: gelu + fp16 store; OUT=0: fp32 nt-store.
template <int OUT>
__global__ __launch_bounds__(256, 2) void gemm4w(
    const signed char* __restrict__ A, const signed char* __restrict__ B,
    void* __restrict__ Cv, int N, int K,
    const float* __restrict__ dq, const float* __restrict__ scales, int sidx) {
    __shared__ __align__(16) char lds[2 * BUFSZ];

    const int tid = threadIdx.x;
    const int lane = tid & 63;
    const int wid = tid >> 6;   // 0..3
    const int wr = wid >> 1;    // 128-row half
    const int wc = wid & 1;     // 64-col half

    // 2D XCD chunking: gx bands; per-XCD = gx/8 bands x all M-rows (gx%8==0)
    const unsigned gx = gridDim.x;
    const unsigned orig = blockIdx.y * gx + blockIdx.x;
    const unsigned bpx = gx >> 3;
    const unsigned xcd = orig & 7, jj = orig >> 3;
    const unsigned bx = xcd * bpx + jj % bpx;
    const unsigned by = jj / bpx;

    const long long M0 = (long long)by * 256;
    const long long N0 = (long long)bx * 128;
    const long long rb = (long long)K;
    const char* Ab = (const char*)A + M0 * rb;
    const char* Bb = (const char*)B + N0 * rb;
    const int nt = K >> 7;

    const int cbs = (((tid & 7) ^ ((tid >> 3) & 7)) << 4);
    const int l15 = lane & 15, l4 = lane >> 4;
    const int swz = (lane & 7) << 4;
    const int acb0 = (l4 * 16) ^ swz;
    const int acb1 = (64 + l4 * 16) ^ swz;
    const int aoff = wr * 16384;            // wave's 128-row A half (16KB)
    const int boff = 32768 + wc * 8192;     // wave's 64-row B half (8KB)

    i32x4 acc[8][4] = {};
    i32x4 aq[4][2], bq[4][2];

    // prologue: buf0 {B(12KB? B=16KB), A0, A1} = 12 gloads; buf1 {B, A0} = 8
    stageN<4>(Bb, rb, 0,   0, lds + 32768, tid, cbs);
    stageN<4>(Ab, rb, 0,   0, lds + 0,     tid, cbs);
    stageN<4>(Ab, rb, 128, 0, lds + 16384, tid, cbs);
    if (nt > 1) {
        stageN<4>(Bb, rb, 0, 1, lds + BUFSZ + 32768, tid, cbs);
        stageN<4>(Ab, rb, 0, 1, lds + BUFSZ,         tid, cbs);
        asm volatile("s_waitcnt vmcnt(8)" ::: "memory");
    } else {
        asm volatile("s_waitcnt vmcnt(0)" ::: "memory");
    }
    __builtin_amdgcn_sched_barrier(0);
    __builtin_amdgcn_s_barrier();

    for (int t = 0; t < nt; ++t) {
        char* cur = lds + (t & 1) * BUFSZ;
        char* nxt = lds + ((t + 1) & 1) * BUFSZ;
        const bool s1 = (t + 1) < nt;
        const bool s2 = (t + 2) < nt;

        // P0: read A-mh0 + B-all; stage A1(t+1)->nxt; QUAD(0,0)
        READ_A(cur, 0);
        READ_B(cur);
        if (s1) stageN<4>(Ab, rb, 128, t + 1, nxt + 16384, tid, cbs);
        LGKM0;
        __builtin_amdgcn_s_setprio(1);
        QUAD(0, 0);
        __builtin_amdgcn_s_setprio(0);
        __builtin_amdgcn_s_barrier();

        // P1: stage B0(t+2)->cur; QUAD(0,1)
        if (s2) stageN<2>(Bb, rb, 0, t + 2, cur + 32768, tid, cbs);
        __builtin_amdgcn_s_setprio(1);
        QUAD(0, 1);
        __builtin_amdgcn_s_setprio(0);
        __builtin_amdgcn_s_barrier();

        // P2: read A-mh1; stage B1(t+2)->cur; QUAD(1,0)
        READ_A(cur, 4);
        if (s2) stageN<2>(Bb, rb, 64, t + 2, cur + 40960, tid, cbs);
        LGKM0;
        __builtin_amdgcn_s_setprio(1);
        QUAD(1, 0);
        __builtin_amdgcn_s_setprio(0);
        __builtin_amdgcn_s_barrier();

        // P3: stage A0(t+2)->cur; QUAD(1,1); counted vmcnt(8)
        if (s2) stageN<4>(Ab, rb, 0, t + 2, cur, tid, cbs);
        __builtin_amdgcn_s_setprio(1);
        QUAD(1, 1);
        __builtin_amdgcn_s_setprio(0);
        if (s2) { asm volatile("s_waitcnt vmcnt(8)" ::: "memory"); }
        else    { asm volatile("s_waitcnt vmcnt(0)" ::: "memory"); }
        __builtin_amdgcn_sched_barrier(0);
        __builtin_amdgcn_s_barrier();
    }

    // epilogue: C/D layout col=lane&15, row=(lane>>4)*4+reg
    const float s = scales[sidx];
#pragma unroll
    for (int mi = 0; mi < 8; ++mi) {
#pragma unroll
        for (int r = 0; r < 4; ++r) {
            const long long m = M0 + wr * 128 + mi * 16 + l4 * 4 + r;
            const float f = dq[m] * s;
#pragma unroll
            for (int ni = 0; ni < 4; ++ni) {
                const long long n = N0 + wc * 64 + ni * 16 + l15;
                float v = (float)acc[mi][ni][r] * f;
                if (OUT) {
                    v = gelu_fast(v);
                    __half hh = __float2half(v);
                    ((unsigned short*)Cv)[m * (long long)N + n] =
                        *(const unsigned short*)&hh;
                } else {
                    __builtin_nontemporal_store(
                        v, (float*)Cv + m * (long long)N + n);
                }
            }
        }
    }
}

// ---------------- launcher ----------------

extern "C" void kernel_launch(void* const* d_in, const int* in_sizes, int n_in,
                              void* d_out, int out_size, void* d_ws, size_t ws_size,
                              hipStream_t stream) {
    (void)n_in; (void)out_size;
    const float* x  = (const float*)d_in[0];
    const float* w1 = (const float*)d_in[1];
    const float* w2 = (const float*)d_in[2];
    float* out = (float*)d_out;

    const int D = 2048, H = 8192;
    const long long M = (long long)in_sizes[0] / D;  // 8192

    char* base = (char*)d_ws;
    size_t off = 0;
    auto alloc = [&](size_t bytes) -> char* {
        char* r = base + off;
        off = (off + bytes + 255) & ~(size_t)255;
        return r;
    };

    const bool fullM = ws_size >= (size_t)236 * 1024 * 1024;
    const long long MC = fullM ? M : M / 2;

    float* part = (float*)alloc(4096 * 4);
    float* scales = (float*)alloc(256);
    float* dqx = (float*)alloc((size_t)M * 4);
    float* dqh = (float*)alloc((size_t)M * 4);
    signed char* wq = (signed char*)alloc((size_t)H * D);      // w1 then w2 overlay
    signed char* xq = (signed char*)alloc((size_t)M * D);
    signed char* hq = (signed char*)alloc((size_t)M * H);      // int8 h (full)
    unsigned short* hf = (unsigned short*)alloc((size_t)MC * H * 2);  // fp16 h

    const int nw4 = H * D / 4;
    abssum2<<<4096, TPB, 0, stream>>>(w1, w2, nw4, part);
    finalize_scales<<<1, TPB, 0, stream>>>(part, scales, 1.0f / (float)(H * D));
    quant_w_i8<<<2048, TPB, 0, stream>>>(w1, wq, scales, 0, nw4);
    quant_x_i8<2><<<(int)M, TPB, 0, stream>>>(x, xq, dqx, D);

    if (fullM) {
        // GEMM1: grid 64 x 32 = 2048 blocks (2/CU, 4 rounds)
        gemm4w<1><<<dim3(H / 128, (int)(M / 256)), 256, 0, stream>>>(
            xq, wq, hf, H, D, dqx, scales, 0);
        quant_h_i8<4><<<(int)M, TPB, 0, stream>>>(hf, hq, dqh, H);
    } else {
        for (int g = 0; g < 2; ++g) {
            const long long m0 = g * MC;
            gemm4w<1><<<dim3(H / 128, (int)(MC / 256)), 256, 0, stream>>>(
                xq + m0 * D, wq, hf, H, D, dqx + m0, scales, 0);
            quant_h_i8<4><<<(int)MC, TPB, 0, stream>>>(hf, hq + m0 * H, dqh + m0, H);
        }
    }

    quant_w_i8<<<2048, TPB, 0, stream>>>(w2, wq, scales, 1, nw4);

    // GEMM2: grid 16 x 32 = 512 blocks (2/CU, 1 round)
    gemm4w<0><<<dim3(D / 128, (int)(M / 256)), 256, 0, stream>>>(
        hq, wq, out, D, H, dqh, scales, 1);
}

// Round 12
// 410.385 us; speedup vs baseline: 1.0506x; 1.0506x over previous
//
#include <hip/hip_runtime.h>
#include <hip/hip_bf16.h>
#include <hip/hip_fp16.h>
#include <stdint.h>

#define TPB 256
#define EPSF 1e-5f

using i32x4 = __attribute__((ext_vector_type(4))) int;

// ---------------- helpers ----------------

__device__ __forceinline__ void gload16(const void* g, void* l) {
    __builtin_amdgcn_global_load_lds(
        (__attribute__((address_space(1))) void*)g,
        (__attribute__((address_space(3))) void*)l,
        16, 0, 0);
}

__device__ __forceinline__ float wave_reduce_sum(float v) {
#pragma unroll
    for (int off = 32; off > 0; off >>= 1) v += __shfl_down(v, off, 64);
    return v;
}

__device__ __forceinline__ float wave_reduce_max(float v) {
#pragma unroll
    for (int off = 32; off > 0; off >>= 1) v = fmaxf(v, __shfl_down(v, off, 64));
    return v;
}

__device__ __forceinline__ int q8(float f, float scale, float lo, float hi) {
    return (int)fminf(fmaxf(rintf(f * scale), lo), hi);
}

// fast GELU: x * sigmoid(2*u), u = sqrt(2/pi)*(x + 0.044715 x^3)
__device__ __forceinline__ float gelu_fast(float x) {
    float x2 = x * x;
    float u = x * (0.7978845608f + 0.0356774081f * x2);
    float e = exp2f(u * -2.8853900817779268f);   // exp(-2u)
    return x * __builtin_amdgcn_rcpf(1.0f + e);
}

// ---------------- scale reduction (deterministic two-pass) ----------------

__global__ void abssum2(const float* __restrict__ w1, const float* __restrict__ w2,
                        int n4, float* __restrict__ part) {
    const bool second = blockIdx.x >= 2048;
    const float4* w4 = (const float4*)(second ? w2 : w1);
    const int b = blockIdx.x & 2047;
    float acc = 0.f;
    for (int i = b * TPB + threadIdx.x; i < n4; i += 2048 * TPB) {
        float4 v = w4[i];
        acc += fabsf(v.x) + fabsf(v.y) + fabsf(v.z) + fabsf(v.w);
    }
    acc = wave_reduce_sum(acc);
    __shared__ float sh[4];
    if ((threadIdx.x & 63) == 0) sh[threadIdx.x >> 6] = acc;
    __syncthreads();
    if (threadIdx.x == 0) part[blockIdx.x] = sh[0] + sh[1] + sh[2] + sh[3];
}

__global__ void finalize_scales(const float* __restrict__ part,
                                float* __restrict__ scales, float inv_n) {
    float a = 0.f, b = 0.f;
    for (int i = threadIdx.x; i < 2048; i += TPB) { a += part[i]; b += part[i + 2048]; }
    a = wave_reduce_sum(a);
    b = wave_reduce_sum(b);
    __shared__ float sa[4], sb[4];
    if ((threadIdx.x & 63) == 0) { sa[threadIdx.x >> 6] = a; sb[threadIdx.x >> 6] = b; }
    __syncthreads();
    if (threadIdx.x == 0) {
        scales[0] = fmaxf((sa[0] + sa[1] + sa[2] + sa[3]) * inv_n, EPSF);
        scales[1] = fmaxf((sb[0] + sb[1] + sb[2] + sb[3]) * inv_n, EPSF);
    }
}

// ---------------- weight ternarization -> int8, MFMA-fragment-PACKED ----------------
// Packed layout: for row n, byte-col c (K = 1<<lk):
//   G=n>>6, r=n&63, ni=r>>4, l15=r&15; t=c>>7, cb=c&127, ks=cb>>6, l4=(cb>>4)&3, b=cb&15
//   addr = ((G*(K>>7)+t)*8 + ni*2+ks)*1024 + (l4*16+l15)*16 + b
// A wave's fragment load is then 64 lanes x 16B contiguous (1KB burst).

__global__ void quant_w_i8p(const float* __restrict__ w,
                            signed char* __restrict__ wq,
                            const float* __restrict__ scales, int sidx,
                            int lk, int n4) {
    const float inv = 1.0f / scales[sidx];
    const int K = 1 << lk;
    const float4* w4 = (const float4*)w;
    for (int i = blockIdx.x * TPB + threadIdx.x; i < n4; i += gridDim.x * TPB) {
        float4 v = w4[i];
        const long long e = (long long)i * 4;         // int8 element index
        const int n = (int)(e >> lk);
        const int c = (int)(e & (K - 1));
        const int G = n >> 6, r = n & 63, ni = r >> 4, l15 = r & 15;
        const int t = c >> 7, cb = c & 127, ks = cb >> 6, l4 = (cb >> 4) & 3, b = cb & 15;
        const long long addr =
            ((((long long)G * (K >> 7) + t) * 8) + ni * 2 + ks) * 1024
            + (l4 * 16 + l15) * 16 + b;
        unsigned p = ((unsigned)(q8(v.x, inv, -1.f, 1.f) & 0xff)) |
                     ((unsigned)(q8(v.y, inv, -1.f, 1.f) & 0xff) << 8) |
                     ((unsigned)(q8(v.z, inv, -1.f, 1.f) & 0xff) << 16) |
                     ((unsigned)(q8(v.w, inv, -1.f, 1.f) & 0xff) << 24);
        *(unsigned*)(wq + addr) = p;
    }
}

// ---------------- per-row activation quant: fp32 -> int8 ----------------

template <int NF4>
__global__ void quant_x_i8(const float* __restrict__ in,
                           signed char* __restrict__ outq,
                           float* __restrict__ dq, int cols) {
    const long long row = blockIdx.x;
    const float4* r4 = (const float4*)(in + row * (long long)cols);
    float4 v[NF4];
    float mx = 0.f;
#pragma unroll
    for (int j = 0; j < NF4; ++j) {
        v[j] = r4[threadIdx.x + TPB * j];
        mx = fmaxf(mx, fmaxf(fmaxf(fabsf(v[j].x), fabsf(v[j].y)),
                             fmaxf(fabsf(v[j].z), fabsf(v[j].w))));
    }
    mx = wave_reduce_max(mx);
    __shared__ float sh[4];
    __shared__ float res;
    if ((threadIdx.x & 63) == 0) sh[threadIdx.x >> 6] = mx;
    __syncthreads();
    if (threadIdx.x == 0) res = fmaxf(fmaxf(sh[0], sh[1]), fmaxf(sh[2], sh[3]));
    __syncthreads();
    const float clipped = fmaxf(res, EPSF);
    const float scale = 127.f / clipped;
    if (threadIdx.x == 0) dq[row] = clipped / 127.f;
    unsigned* oq = (unsigned*)(outq + row * (long long)cols);
#pragma unroll
    for (int j = 0; j < NF4; ++j) {
        unsigned p = ((unsigned)(q8(v[j].x, scale, -128.f, 127.f) & 0xff)) |
                     ((unsigned)(q8(v[j].y, scale, -128.f, 127.f) & 0xff) << 8) |
                     ((unsigned)(q8(v[j].z, scale, -128.f, 127.f) & 0xff) << 16) |
                     ((unsigned)(q8(v[j].w, scale, -128.f, 127.f) & 0xff) << 24);
        oq[threadIdx.x + TPB * j] = p;
    }
}

// ---------------- per-row quant: fp16 -> int8 (for h) ----------------

template <int NJ>
__global__ void quant_h_i8(const unsigned short* __restrict__ h,
                           signed char* __restrict__ outq,
                           float* __restrict__ dq, int cols) {
    const long long row = blockIdx.x;
    const unsigned short* rp = h + row * (long long)cols;
    uint4 v[NJ];
    float mx = 0.f;
#pragma unroll
    for (int j = 0; j < NJ; ++j) {
        v[j] = *(const uint4*)(rp + (threadIdx.x + TPB * j) * 8);
        const unsigned* u = (const unsigned*)&v[j];
#pragma unroll
        for (int e = 0; e < 4; ++e) {
            float2 f2 = __half22float2(*(const __half2*)&u[e]);
            mx = fmaxf(mx, fmaxf(fabsf(f2.x), fabsf(f2.y)));
        }
    }
    mx = wave_reduce_max(mx);
    __shared__ float sh[4];
    __shared__ float res;
    if ((threadIdx.x & 63) == 0) sh[threadIdx.x >> 6] = mx;
    __syncthreads();
    if (threadIdx.x == 0) res = fmaxf(fmaxf(sh[0], sh[1]), fmaxf(sh[2], sh[3]));
    __syncthreads();
    const float clipped = fmaxf(res, EPSF);
    const float scale = 127.f / clipped;
    if (threadIdx.x == 0) dq[row] = clipped / 127.f;
    uint2* oq = (uint2*)(outq + row * (long long)cols);
#pragma unroll
    for (int j = 0; j < NJ; ++j) {
        const unsigned* u = (const unsigned*)&v[j];
        unsigned o[2] = {0, 0};
#pragma unroll
        for (int e = 0; e < 4; ++e) {
            float2 f2 = __half22float2(*(const __half2*)&u[e]);
            unsigned b0 = (unsigned)(q8(f2.x, scale, -128.f, 127.f) & 0xff);
            unsigned b1 = (unsigned)(q8(f2.y, scale, -128.f, 127.f) & 0xff);
            o[e >> 1] |= (b0 | (b1 << 8)) << ((e & 1) * 16);
        }
        oq[threadIdx.x + TPB * j] = *(uint2*)o;
    }
}

// ---------------- GEMM: A row-major (LDS-staged), B fragment-packed (global) ----------------

__device__ __forceinline__ void stage_half(const char* Xb, long long rowB, int prow,
                                           int tk, char* dst, int tid, int cbs) {
    const long long gc = (long long)tk * 128 + cbs;
    const int r = tid >> 3;
    gload16(Xb + (long long)(prow + r) * rowB + gc, dst + tid * 16);
    gload16(Xb + (long long)(prow + 64 + r) * rowB + gc, dst + 8192 + tid * 16);
}

#define QUAD(MB, NB)                                                            \
    _Pragma("unroll") for (int mi = 0; mi < 4; ++mi)                            \
    _Pragma("unroll") for (int ni = 0; ni < 2; ++ni)                            \
    _Pragma("unroll") for (int ks = 0; ks < 2; ++ks)                            \
        acc[(MB)*4 + mi][(NB)*2 + ni] = __builtin_amdgcn_mfma_i32_16x16x64_i8(  \
            aq[mi][ks], bqf[((((NB)*2 + ni) << 1) + ks)],                       \
            acc[(MB)*4 + mi][(NB)*2 + ni], 0, 0, 0);

#define READ_A(BUF, base_mi)                                                    \
    _Pragma("unroll") for (int mi = 0; mi < 4; ++mi) {                          \
        const char* p = (BUF) + aoff + ((mi + (base_mi)) * 16 + l15) * 128;     \
        aq[mi][0] = *(const i32x4*)(p + acb0);                                  \
        aq[mi][1] = *(const i32x4*)(p + acb1);                                  \
    }

#define LOAD_B(T)                                                               \
    do { const char* bp_ = Bg + (long long)(T) * 8192 + lane * 16;              \
        _Pragma("unroll") for (int f = 0; f < 8; ++f)                           \
            bqf[f] = *(const i32x4*)(bp_ + f * 1024);                           \
        __builtin_amdgcn_sched_barrier(0); } while (0)

#define LGKM0 do { asm volatile("s_waitcnt lgkmcnt(0)" ::: "memory");           \
                   __builtin_amdgcn_sched_barrier(0); } while (0)

#define BUFSZ 32768

// 256x256 tile, 8 waves (2Mx4N), BK=128 i8. A double-buffered in 64KB LDS;
// B fragment-packed, loaded global->VGPR (coalesced 1KB bursts, L2-resident).
// ONE barrier per K-tile, placed AFTER each wave's vmcnt(8) drain of its
// buf(t+1) stages and BEFORE the mh0(t+1) read-ahead + A0(t+2) stage —
// cross-wave invariant: stages drained by issuer before a barrier that
// precedes any wave's reads (R11 bug #2 fixed). Prologue stages BOTH A
// halves before the first barrier (R11 bug #1 fixed).
template <int OUT>
__global__ __launch_bounds__(512, 2) void gemmP(
    const signed char* __restrict__ A, const signed char* __restrict__ Bp,
    void* __restrict__ Cv, int N, int K,
    const float* __restrict__ dq, const float* __restrict__ scales, int sidx) {
    __shared__ __align__(16) char lds[2 * BUFSZ];

    const int tid = threadIdx.x;
    const int lane = tid & 63;
    const int wid = tid >> 6;
    const int wr = wid >> 2;     // 128-row half of A tile
    const int wc = wid & 3;      // 64-row group of B tile

    // 2D XCD chunk (gx % 8 == 0): XCD owns gx/8 N-bands x all M-groups
    const unsigned gx = gridDim.x;
    const unsigned orig = blockIdx.y * gx + blockIdx.x;
    const unsigned bpx = gx >> 3;
    const unsigned xcd = orig & 7, jj = orig >> 3;
    const unsigned bx = xcd * bpx + jj % bpx;
    const unsigned by = jj / bpx;

    const long long M0 = (long long)by * 256;
    const long long N0 = (long long)bx * 256;
    const long long rb = (long long)K;
    const char* Ab = (const char*)A + M0 * rb;
    const char* Bg = (const char*)Bp +
        ((long long)((N0 >> 6) + wc) * (K >> 7)) * 8192;  // wave's packed B group
    const int nt = K >> 7;

    const int cbs = (((tid & 7) ^ ((tid >> 3) & 7)) << 4);
    const int l15 = lane & 15, l4 = lane >> 4;
    const int swz = (lane & 7) << 4;
    const int acb0 = (l4 * 16) ^ swz;
    const int acb1 = (64 + l4 * 16) ^ swz;
    const int aoff = wr * 16384;

    i32x4 acc[8][4] = {};
    i32x4 aq[4][2];
    i32x4 bqf[8];

    // prologue: stage BOTH halves of tile 0; drain; barrier; then reads
    stage_half(Ab, rb, 0,   0, lds + 0,     tid, cbs);   // A0(0)
    stage_half(Ab, rb, 128, 0, lds + 16384, tid, cbs);   // A1(0)
    asm volatile("s_waitcnt vmcnt(0)" ::: "memory");
    __builtin_amdgcn_sched_barrier(0);
    __builtin_amdgcn_s_barrier();
    READ_A(lds, 0);                                      // mh0(0) — both halves valid
    LOAD_B(0);                                           // B(0) x8
    if (nt > 1) stage_half(Ab, rb, 0, 1, lds + BUFSZ, tid, cbs);  // A0(1)
    // FIFO: [B(0)^8, A0(1)^2]

    for (int t = 0; t < nt; ++t) {
        char* cur = lds + (t & 1) * BUFSZ;
        char* nxt = lds + ((t + 1) & 1) * BUFSZ;
        const bool s1 = (t + 1) < nt;
        const bool s2 = (t + 2) < nt;

        if (s1) { asm volatile("s_waitcnt vmcnt(2)" ::: "memory"); }
        else    { asm volatile("s_waitcnt vmcnt(0)" ::: "memory"); }
        __builtin_amdgcn_sched_barrier(0);
        LGKM0;                       // mh0 read-ahead drained
        __builtin_amdgcn_s_setprio(1);
        QUAD(0, 0);
        QUAD(0, 1);
        __builtin_amdgcn_s_setprio(0);

        READ_A(cur, 4);              // mh1(t)
        if (s1) stage_half(Ab, rb, 128, t + 1, nxt + 16384, tid, cbs);  // A1(t+1)
        LGKM0;
        __builtin_amdgcn_s_setprio(1);
        QUAD(1, 0);
        QUAD(1, 1);
        __builtin_amdgcn_s_setprio(0);

        if (s1) {
            LOAD_B(t + 1);           // bqf WAR-free after QUAD(1,1)
            asm volatile("s_waitcnt vmcnt(8)" ::: "memory");  // own A0/A1(t+1) done
            __builtin_amdgcn_sched_barrier(0);
        }
        __builtin_amdgcn_s_barrier();    // ALL waves' buf(t+1) stages complete
        if (s1) READ_A(nxt, 0);          // mh0(t+1) read-ahead (post-barrier: safe)
        if (s2) stage_half(Ab, rb, 0, t + 2, cur, tid, cbs);  // A0(t+2)
    }

    // epilogue: C/D layout col=lane&15, row=(lane>>4)*4+reg
    const float s = scales[sidx];
#pragma unroll
    for (int mi = 0; mi < 8; ++mi) {
#pragma unroll
        for (int r = 0; r < 4; ++r) {
            const long long m = M0 + wr * 128 + mi * 16 + l4 * 4 + r;
            const float f = dq[m] * s;
#pragma unroll
            for (int ni = 0; ni < 4; ++ni) {
                const long long n = N0 + wc * 64 + ni * 16 + l15;
                float v = (float)acc[mi][ni][r] * f;
                if (OUT) {
                    v = gelu_fast(v);
                    __half hh = __float2half(v);
                    ((unsigned short*)Cv)[m * (long long)N + n] =
                        *(const unsigned short*)&hh;
                } else {
                    __builtin_nontemporal_store(
                        v, (float*)Cv + m * (long long)N + n);
                }
            }
        }
    }
}

// ---------------- launcher ----------------

extern "C" void kernel_launch(void* const* d_in, const int* in_sizes, int n_in,
                              void* d_out, int out_size, void* d_ws, size_t ws_size,
                              hipStream_t stream) {
    (void)n_in; (void)out_size;
    const float* x  = (const float*)d_in[0];
    const float* w1 = (const float*)d_in[1];
    const float* w2 = (const float*)d_in[2];
    float* out = (float*)d_out;

    const int D = 2048, H = 8192;
    const long long M = (long long)in_sizes[0] / D;  // 8192

    char* base = (char*)d_ws;
    size_t off = 0;
    auto alloc = [&](size_t bytes) -> char* {
        char* r = base + off;
        off = (off + bytes + 255) & ~(size_t)255;
        return r;
    };

    const bool fullM = ws_size >= (size_t)236 * 1024 * 1024;
    const long long MC = fullM ? M : M / 2;

    float* part = (float*)alloc(4096 * 4);
    float* scales = (float*)alloc(256);
    float* dqx = (float*)alloc((size_t)M * 4);
    float* dqh = (float*)alloc((size_t)M * 4);
    signed char* wq = (signed char*)alloc((size_t)H * D);      // packed; w1 then w2
    signed char* xq = (signed char*)alloc((size_t)M * D);
    signed char* hq = (signed char*)alloc((size_t)M * H);      // int8 h (full)
    unsigned short* hf = (unsigned short*)alloc((size_t)MC * H * 2);  // fp16 h

    const int nw4 = H * D / 4;
    abssum2<<<4096, TPB, 0, stream>>>(w1, w2, nw4, part);
    finalize_scales<<<1, TPB, 0, stream>>>(part, scales, 1.0f / (float)(H * D));
    quant_w_i8p<<<2048, TPB, 0, stream>>>(w1, wq, scales, 0, 11, nw4);  // K=2048
    quant_x_i8<2><<<(int)M, TPB, 0, stream>>>(x, xq, dqx, D);

    if (fullM) {
        // GEMM1: grid 32x32 = 1024 blocks, 4 rounds
        gemmP<1><<<dim3(H / 256, (int)(M / 256)), 512, 0, stream>>>(
            xq, wq, hf, H, D, dqx, scales, 0);
        quant_h_i8<4><<<(int)M, TPB, 0, stream>>>(hf, hq, dqh, H);
    } else {
        for (int g = 0; g < 2; ++g) {
            const long long m0 = g * MC;
            gemmP<1><<<dim3(H / 256, (int)(MC / 256)), 512, 0, stream>>>(
                xq + m0 * D, wq, hf, H, D, dqx + m0, scales, 0);
            quant_h_i8<4><<<(int)MC, TPB, 0, stream>>>(hf, hq + m0 * H, dqh + m0, H);
        }
    }

    quant_w_i8p<<<2048, TPB, 0, stream>>>(w2, wq, scales, 1, 13, nw4);  // K=8192

    // GEMM2: grid 8x32 = 256 blocks, 1 round
    gemmP<0><<<dim3(D / 256, (int)(M / 256)), 512, 0, stream>>>(
        hq, wq, out, D, H, dqh, scales, 1);
}

// Round 13
// 357.705 us; speedup vs baseline: 1.2053x; 1.1473x over previous
//
#include <hip/hip_runtime.h>
#include <hip/hip_bf16.h>
#include <hip/hip_fp16.h>
#include <stdint.h>

#define TPB 256
#define EPSF 1e-5f

using i32x4 = __attribute__((ext_vector_type(4))) int;

// ---------------- helpers ----------------

__device__ __forceinline__ void gload16(const void* g, void* l) {
    __builtin_amdgcn_global_load_lds(
        (__attribute__((address_space(1))) void*)g,
        (__attribute__((address_space(3))) void*)l,
        16, 0, 0);
}

__device__ __forceinline__ float wave_reduce_sum(float v) {
#pragma unroll
    for (int off = 32; off > 0; off >>= 1) v += __shfl_down(v, off, 64);
    return v;
}

__device__ __forceinline__ float wave_reduce_max(float v) {
#pragma unroll
    for (int off = 32; off > 0; off >>= 1) v = fmaxf(v, __shfl_down(v, off, 64));
    return v;
}

__device__ __forceinline__ int q8(float f, float scale, float lo, float hi) {
    return (int)fminf(fmaxf(rintf(f * scale), lo), hi);
}

// fast GELU: x * sigmoid(2*u), u = sqrt(2/pi)*(x + 0.044715 x^3)
__device__ __forceinline__ float gelu_fast(float x) {
    float x2 = x * x;
    float u = x * (0.7978845608f + 0.0356774081f * x2);
    float e = exp2f(u * -2.8853900817779268f);   // exp(-2u)
    return x * __builtin_amdgcn_rcpf(1.0f + e);
}

// ---------------- scale reduction (deterministic two-pass) ----------------

__global__ void abssum2(const float* __restrict__ w1, const float* __restrict__ w2,
                        int n4, float* __restrict__ part) {
    const bool second = blockIdx.x >= 2048;
    const float4* w4 = (const float4*)(second ? w2 : w1);
    const int b = blockIdx.x & 2047;
    float acc = 0.f;
    for (int i = b * TPB + threadIdx.x; i < n4; i += 2048 * TPB) {
        float4 v = w4[i];
        acc += fabsf(v.x) + fabsf(v.y) + fabsf(v.z) + fabsf(v.w);
    }
    acc = wave_reduce_sum(acc);
    __shared__ float sh[4];
    if ((threadIdx.x & 63) == 0) sh[threadIdx.x >> 6] = acc;
    __syncthreads();
    if (threadIdx.x == 0) part[blockIdx.x] = sh[0] + sh[1] + sh[2] + sh[3];
}

__global__ void finalize_scales(const float* __restrict__ part,
                                float* __restrict__ scales, float inv_n) {
    float a = 0.f, b = 0.f;
    for (int i = threadIdx.x; i < 2048; i += TPB) { a += part[i]; b += part[i + 2048]; }
    a = wave_reduce_sum(a);
    b = wave_reduce_sum(b);
    __shared__ float sa[4], sb[4];
    if ((threadIdx.x & 63) == 0) { sa[threadIdx.x >> 6] = a; sb[threadIdx.x >> 6] = b; }
    __syncthreads();
    if (threadIdx.x == 0) {
        scales[0] = fmaxf((sa[0] + sa[1] + sa[2] + sa[3]) * inv_n, EPSF);
        scales[1] = fmaxf((sb[0] + sb[1] + sb[2] + sb[3]) * inv_n, EPSF);
    }
}

// ---------------- weight ternarization -> int8 ----------------

__global__ void quant_w_i8(const float* __restrict__ w,
                           signed char* __restrict__ wq,
                           const float* __restrict__ scales, int sidx, int n4) {
    const float inv = 1.0f / scales[sidx];
    const float4* w4 = (const float4*)w;
    unsigned* oq = (unsigned*)wq;
    for (int i = blockIdx.x * TPB + threadIdx.x; i < n4; i += gridDim.x * TPB) {
        float4 v = w4[i];
        unsigned p = ((unsigned)(q8(v.x, inv, -1.f, 1.f) & 0xff)) |
                     ((unsigned)(q8(v.y, inv, -1.f, 1.f) & 0xff) << 8) |
                     ((unsigned)(q8(v.z, inv, -1.f, 1.f) & 0xff) << 16) |
                     ((unsigned)(q8(v.w, inv, -1.f, 1.f) & 0xff) << 24);
        oq[i] = p;
    }
}

// ---------------- per-row activation quant: fp32 -> int8 ----------------

template <int NF4>
__global__ void quant_x_i8(const float* __restrict__ in,
                           signed char* __restrict__ outq,
                           float* __restrict__ dq, int cols) {
    const long long row = blockIdx.x;
    const float4* r4 = (const float4*)(in + row * (long long)cols);
    float4 v[NF4];
    float mx = 0.f;
#pragma unroll
    for (int j = 0; j < NF4; ++j) {
        v[j] = r4[threadIdx.x + TPB * j];
        mx = fmaxf(mx, fmaxf(fmaxf(fabsf(v[j].x), fabsf(v[j].y)),
                             fmaxf(fabsf(v[j].z), fabsf(v[j].w))));
    }
    mx = wave_reduce_max(mx);
    __shared__ float sh[4];
    __shared__ float res;
    if ((threadIdx.x & 63) == 0) sh[threadIdx.x >> 6] = mx;
    __syncthreads();
    if (threadIdx.x == 0) res = fmaxf(fmaxf(sh[0], sh[1]), fmaxf(sh[2], sh[3]));
    __syncthreads();
    const float clipped = fmaxf(res, EPSF);
    const float scale = 127.f / clipped;
    if (threadIdx.x == 0) dq[row] = clipped / 127.f;
    unsigned* oq = (unsigned*)(outq + row * (long long)cols);
#pragma unroll
    for (int j = 0; j < NF4; ++j) {
        unsigned p = ((unsigned)(q8(v[j].x, scale, -128.f, 127.f) & 0xff)) |
                     ((unsigned)(q8(v[j].y, scale, -128.f, 127.f) & 0xff) << 8) |
                     ((unsigned)(q8(v[j].z, scale, -128.f, 127.f) & 0xff) << 16) |
                     ((unsigned)(q8(v[j].w, scale, -128.f, 127.f) & 0xff) << 24);
        oq[threadIdx.x + TPB * j] = p;
    }
}

// ---------------- per-row quant: fp16 -> int8 (for h) ----------------

template <int NJ>
__global__ void quant_h_i8(const unsigned short* __restrict__ h,
                           signed char* __restrict__ outq,
                           float* __restrict__ dq, int cols) {
    const long long row = blockIdx.x;
    const unsigned short* rp = h + row * (long long)cols;
    uint4 v[NJ];
    float mx = 0.f;
#pragma unroll
    for (int j = 0; j < NJ; ++j) {
        v[j] = *(const uint4*)(rp + (threadIdx.x + TPB * j) * 8);
        const unsigned* u = (const unsigned*)&v[j];
#pragma unroll
        for (int e = 0; e < 4; ++e) {
            float2 f2 = __half22float2(*(const __half2*)&u[e]);
            mx = fmaxf(mx, fmaxf(fabsf(f2.x), fabsf(f2.y)));
        }
    }
    mx = wave_reduce_max(mx);
    __shared__ float sh[4];
    __shared__ float res;
    if ((threadIdx.x & 63) == 0) sh[threadIdx.x >> 6] = mx;
    __syncthreads();
    if (threadIdx.x == 0) res = fmaxf(fmaxf(sh[0], sh[1]), fmaxf(sh[2], sh[3]));
    __syncthreads();
    const float clipped = fmaxf(res, EPSF);
    const float scale = 127.f / clipped;
    if (threadIdx.x == 0) dq[row] = clipped / 127.f;
    uint2* oq = (uint2*)(outq + row * (long long)cols);
#pragma unroll
    for (int j = 0; j < NJ; ++j) {
        const unsigned* u = (const unsigned*)&v[j];
        unsigned o[2] = {0, 0};
#pragma unroll
        for (int e = 0; e < 4; ++e) {
            float2 f2 = __half22float2(*(const __half2*)&u[e]);
            unsigned b0 = (unsigned)(q8(f2.x, scale, -128.f, 127.f) & 0xff);
            unsigned b1 = (unsigned)(q8(f2.y, scale, -128.f, 127.f) & 0xff);
            o[e >> 1] |= (b0 | (b1 << 8)) << ((e & 1) * 16);
        }
        oq[threadIdx.x + TPB * j] = *(uint2*)o;
    }
}

// ---------------- shared GEMM pieces ----------------

__device__ __forceinline__ void stage_half(const char* Xb, long long rowB, int prow,
                                           int tk, char* dst, int tid, int cbs) {
    const long long gc = (long long)tk * 128 + cbs;
    const int r = tid >> 3;
    gload16(Xb + (long long)(prow + r) * rowB + gc, dst + tid * 16);
    gload16(Xb + (long long)(prow + 64 + r) * rowB + gc, dst + 8192 + tid * 16);
}

#define QUAD(MB, NB)                                                            \
    _Pragma("unroll") for (int mi = 0; mi < 4; ++mi)                            \
    _Pragma("unroll") for (int ni = 0; ni < 2; ++ni)                            \
    _Pragma("unroll") for (int ks = 0; ks < 2; ++ks)                            \
        acc[(MB)*4 + mi][(NB)*2 + ni] = __builtin_amdgcn_mfma_i32_16x16x64_i8(  \
            aq[mi][ks], bq[(NB)*2 + ni][ks], acc[(MB)*4 + mi][(NB)*2 + ni], 0, 0, 0);

#define READ_A(BUF, base_mi)                                                    \
    _Pragma("unroll") for (int mi = 0; mi < 4; ++mi) {                          \
        const char* p = (BUF) + aoff + ((mi + (base_mi)) * 16 + l15) * 128;     \
        aq[mi][0] = *(const i32x4*)(p + acb0);                                  \
        aq[mi][1] = *(const i32x4*)(p + acb1);                                  \
    }
#define READ_B(BUF, n0i, n1i)                                                   \
    _Pragma("unroll") for (int ni = (n0i); ni < (n1i); ++ni) {                  \
        const char* p = (BUF) + boff + (ni * 16 + l15) * 128;                   \
        bq[ni][0] = *(const i32x4*)(p + acb0);                                  \
        bq[ni][1] = *(const i32x4*)(p + acb1);                                  \
    }

#define LGKM(N) do { asm volatile("s_waitcnt lgkmcnt(" #N ")" ::: "memory");    \
                     __builtin_amdgcn_sched_barrier(0); } while (0)

// split epilogue for gemm1p: rows [MLO,MHI), gelu + fp16 store, zero acc
#define EMIT1(MLO, MHI, M0V)                                                    \
    _Pragma("unroll") for (int mi = (MLO); mi < (MHI); ++mi) {                  \
        _Pragma("unroll") for (int r = 0; r < 4; ++r) {                         \
            const long long m = (M0V) + wr * 128 + mi * 16 + l4 * 4 + r;        \
            const float f = dq[m] * s;                                          \
            _Pragma("unroll") for (int ni = 0; ni < 4; ++ni) {                  \
                const long long n = n0 + wc * 64 + ni * 16 + l15;               \
                float v = gelu_fast((float)acc[mi][ni][r] * f);                 \
                __half hh = __float2half(v);                                    \
                C[m * (long long)N + n] = *(const unsigned short*)&hh;          \
                acc[mi][ni][r] = 0;                                             \
            }                                                                   \
        }                                                                       \
    }

// ---------------- persistent GEMM1: x@w1^T -> gelu -> fp16 h ----------------
// R9 read-ahead skeleton. XCD chunk REMAPPED (R13): XCD owns 4 N-bands x all
// 8 M-groups -> B/XCD = 4 x 512KB = 2MB (was 4MB = L2-sized, evicted by
// A-streaming between M-rounds; FETCH showed 66MB of B re-reads).

__global__ __launch_bounds__(512, 2) void gemm1p(
    const signed char* __restrict__ A, const signed char* __restrict__ B,
    unsigned short* __restrict__ C, int N, int K,
    const float* __restrict__ dq, const float* __restrict__ scales, int ntile) {
    __shared__ __align__(16) char lds[131072];

    const int tid = threadIdx.x;
    const int lane = tid & 63;
    const int wid = tid >> 6;
    const int wr = wid >> 2;
    const int wc = wid & 3;

    // grid 32x8 = 256 blocks; XCD = orig & 7. XCD k -> bands [4k, 4k+4), all groups.
    const unsigned orig = blockIdx.y * gridDim.x + blockIdx.x;
    const unsigned xk = orig & 7, j = orig >> 3;
    const unsigned bx = xk * 4 + (j & 3);      // N band 0..31 (4 per XCD)
    const unsigned byg = j >> 2;               // M group 0..7

    const int n0 = (int)bx * 256;
    const long long rb = (long long)K;
    const char* Ab = (const char*)A;
    const char* Bb = (const char*)B;

    const int NTT = ntile << 4;

    const int cbs = (((tid & 7) ^ ((tid >> 3) & 7)) << 4);
    const int l15 = lane & 15, l4 = lane >> 4;
    const int swz = (lane & 7) << 4;
    const int acb0 = (l4 * 16) ^ swz;
    const int acb1 = (64 + l4 * 16) ^ swz;
    const int aoff = wr * 16384;
    const int boff = 32768 + (wc >> 1) * 16384 + (wc & 1) * 8192;

    i32x4 acc[8][4] = {};
    i32x4 aq[4][2], bq[4][2];

    auto mrow = [&](int v) -> int { return ((int)byg * ntile + (v >> 4)) * 256; };

    // prologue: buf0 {B0,B1,A0,A1}, buf1 {B0,B1,A0}; vmcnt(6) retires buf0
    stage_half(Bb, rb, n0, 0, lds + 32768, tid, cbs);
    stage_half(Bb, rb, n0 + 128, 0, lds + 32768 + 16384, tid, cbs);
    stage_half(Ab, rb, mrow(0), 0, lds + 0, tid, cbs);
    stage_half(Ab, rb, mrow(0) + 128, 0, lds + 16384, tid, cbs);
    stage_half(Bb, rb, n0, 1, lds + 65536 + 32768, tid, cbs);
    stage_half(Bb, rb, n0 + 128, 1, lds + 65536 + 32768 + 16384, tid, cbs);
    stage_half(Ab, rb, mrow(1), 1, lds + 65536, tid, cbs);
    asm volatile("s_waitcnt vmcnt(6)" ::: "memory");
    __builtin_amdgcn_sched_barrier(0);
    __builtin_amdgcn_s_barrier();
    READ_A(lds, 0);        // mh0 of tile chunk 0
    READ_B(lds, 0, 2);     // B[0..1]

    const float s = scales[0];

    for (int vt = 0; vt < NTT; ++vt) {
        char* cur = lds + ((vt & 1) << 16);
        char* nxt = lds + (((vt + 1) & 1) << 16);
        const bool s1 = (vt + 1) < NTT;
        const bool s2 = (vt + 2) < NTT;
        const int kk = vt & 15;
        const int k1 = (vt + 1) & 15;
        const int k2 = (vt + 2) & 15;

        // P0: stage A1(vt+1)->nxt; read bqB=cur B[2..3]; emit_hi(prev tile)
        if (s1) stage_half(Ab, rb, mrow(vt + 1) + 128, k1, nxt + 16384, tid, cbs);
        READ_B(cur, 2, 4);
        if (kk == 0 && vt > 0) { EMIT1(4, 8, mrow(vt - 1)); }
        __builtin_amdgcn_s_barrier();
        LGKM(4);   // drain aq(mh0)+bqA (prev P3); leave bqB in flight
        __builtin_amdgcn_s_setprio(1);
        QUAD(0, 0);
        __builtin_amdgcn_s_setprio(0);

        // P1: spacer barrier (orders bqA/bqB drains vs P2 B-stages)
        __builtin_amdgcn_s_barrier();
        LGKM(0);   // bqB (latency hidden by P0 QUAD + barrier)
        __builtin_amdgcn_s_setprio(1);
        QUAD(0, 1);
        __builtin_amdgcn_s_setprio(0);

        // P2: stage B0+B1(vt+2)->cur; read aq=cur A-mh1; emit_lo(this tile)
        if (s2) {
            stage_half(Bb, rb, n0, k2, cur + 32768, tid, cbs);
            stage_half(Bb, rb, n0 + 128, k2, cur + 32768 + 16384, tid, cbs);
        }
        READ_A(cur, 4);
        if (kk == 15) { EMIT1(0, 4, mrow(vt)); }
        __builtin_amdgcn_s_barrier();
        LGKM(0);   // aq(mh1)
        __builtin_amdgcn_s_setprio(1);
        QUAD(1, 0);
        __builtin_amdgcn_s_setprio(0);

        // P3: vmcnt; barrier; stage A0(vt+2)->cur; QUAD(1,1); read-ahead nxt
        if (s2) { asm volatile("s_waitcnt vmcnt(4)" ::: "memory"); }
        else    { asm volatile("s_waitcnt vmcnt(0)" ::: "memory"); }
        __builtin_amdgcn_sched_barrier(0);
        __builtin_amdgcn_s_barrier();
        if (s2) stage_half(Ab, rb, mrow(vt + 2), k2, cur, tid, cbs);
        __builtin_amdgcn_s_setprio(1);
        QUAD(1, 1);
        __builtin_amdgcn_s_setprio(0);
        if (s1) {
            READ_A(nxt, 0);      // next step mh0 (WAR on aq after QUAD(1,1))
            READ_B(nxt, 0, 2);   // next step B[0..1]
        }
    }

    // tail: hi half of the last tile
    { EMIT1(4, 8, mrow(NTT - 1)); }
}

// ---------------- 256x256 read-ahead i8 GEMM2 (R9 exact) ----------------

#define EMIT2(MLO, MHI)                                                         \
    _Pragma("unroll") for (int mi = (MLO); mi < (MHI); ++mi) {                  \
        _Pragma("unroll") for (int r = 0; r < 4; ++r) {                         \
            const long long m = M0 + wr * 128 + mi * 16 + l4 * 4 + r;           \
            const float f = dq[m] * s;                                          \
            _Pragma("unroll") for (int ni = 0; ni < 4; ++ni) {                  \
                const long long n = N0 + wc * 64 + ni * 16 + l15;               \
                __builtin_nontemporal_store(                                    \
                    (float)acc[mi][ni][r] * f, C + m * (long long)N + n);       \
            }                                                                   \
        }                                                                       \
    }

__global__ __launch_bounds__(512, 2) void gemm2k(
    const signed char* __restrict__ A, const signed char* __restrict__ B,
    float* __restrict__ C, int N, int K,
    const float* __restrict__ dq, const float* __restrict__ scales) {
    __shared__ __align__(16) char lds[131072];

    const int tid = threadIdx.x;
    const int lane = tid & 63;
    const int wid = tid >> 6;
    const int wr = wid >> 2;
    const int wc = wid & 3;

    const unsigned gx = gridDim.x;
    unsigned lin = blockIdx.y * gx + blockIdx.x;
    const unsigned qq = (gx * gridDim.y) >> 3;
    lin = (lin & 7) * qq + (lin >> 3);
    const unsigned bx = lin % gx;
    const unsigned by = lin / gx;

    const long long M0 = (long long)by * 256;
    const long long N0 = (long long)bx * 256;
    const long long rb = (long long)K;
    const char* Ab = (const char*)A + M0 * rb;
    const char* Bb = (const char*)B + N0 * rb;
    const int nt = K >> 7;

    const int cbs = (((tid & 7) ^ ((tid >> 3) & 7)) << 4);
    const int l15 = lane & 15, l4 = lane >> 4;
    const int swz = (lane & 7) << 4;
    const int acb0 = (l4 * 16) ^ swz;
    const int acb1 = (64 + l4 * 16) ^ swz;
    const int aoff = wr * 16384;
    const int boff = 32768 + (wc >> 1) * 16384 + (wc & 1) * 8192;

    i32x4 acc[8][4] = {};
    i32x4 aq[4][2], bq[4][2];

    stage_half(Bb, rb, 0,   0, lds + 32768,         tid, cbs);
    stage_half(Bb, rb, 128, 0, lds + 32768 + 16384, tid, cbs);
    stage_half(Ab, rb, 0,   0, lds + 0,             tid, cbs);
    stage_half(Ab, rb, 128, 0, lds + 16384,         tid, cbs);
    stage_half(Bb, rb, 0,   1, lds + 65536 + 32768,         tid, cbs);
    stage_half(Bb, rb, 128, 1, lds + 65536 + 32768 + 16384, tid, cbs);
    stage_half(Ab, rb, 0,   1, lds + 65536,                 tid, cbs);
    asm volatile("s_waitcnt vmcnt(6)" ::: "memory");
    __builtin_amdgcn_sched_barrier(0);
    __builtin_amdgcn_s_barrier();
    READ_A(lds, 0);
    READ_B(lds, 0, 2);

    const float s = scales[1];

    for (int t = 0; t < nt; ++t) {
        char* cur = lds + ((t & 1) << 16);
        char* nxt = lds + (((t + 1) & 1) << 16);
        const bool s1 = (t + 1) < nt;
        const bool s2 = (t + 2) < nt;

        // P0
        if (s1) stage_half(Ab, rb, 128, t + 1, nxt + 16384, tid, cbs);
        READ_B(cur, 2, 4);
        __builtin_amdgcn_s_barrier();
        LGKM(4);
        __builtin_amdgcn_s_setprio(1);
        QUAD(0, 0);
        __builtin_amdgcn_s_setprio(0);

        // P1
        __builtin_amdgcn_s_barrier();
        LGKM(0);
        __builtin_amdgcn_s_setprio(1);
        QUAD(0, 1);
        __builtin_amdgcn_s_setprio(0);

        // P2
        if (s2) {
            stage_half(Bb, rb, 0, t + 2, cur + 32768, tid, cbs);
            stage_half(Bb, rb, 128, t + 2, cur + 32768 + 16384, tid, cbs);
        }
        READ_A(cur, 4);
        if (t == nt - 1) { EMIT2(0, 4); }
        __builtin_amdgcn_s_barrier();
        LGKM(0);
        __builtin_amdgcn_s_setprio(1);
        QUAD(1, 0);
        __builtin_amdgcn_s_setprio(0);

        // P3
        if (s2) { asm volatile("s_waitcnt vmcnt(4)" ::: "memory"); }
        else    { asm volatile("s_waitcnt vmcnt(0)" ::: "memory"); }
        __builtin_amdgcn_sched_barrier(0);
        __builtin_amdgcn_s_barrier();
        if (s2) stage_half(Ab, rb, 0, t + 2, cur, tid, cbs);
        __builtin_amdgcn_s_setprio(1);
        QUAD(1, 1);
        __builtin_amdgcn_s_setprio(0);
        if (s1) {
            READ_A(nxt, 0);
            READ_B(nxt, 0, 2);
        }
    }

    { EMIT2(4, 8); }
}

// ---------------- launcher ----------------

extern "C" void kernel_launch(void* const* d_in, const int* in_sizes, int n_in,
                              void* d_out, int out_size, void* d_ws, size_t ws_size,
                              hipStream_t stream) {
    (void)n_in; (void)out_size;
    const float* x  = (const float*)d_in[0];
    const float* w1 = (const float*)d_in[1];
    const float* w2 = (const float*)d_in[2];
    float* out = (float*)d_out;

    const int D = 2048, H = 8192;
    const long long M = (long long)in_sizes[0] / D;  // 8192

    char* base = (char*)d_ws;
    size_t off = 0;
    auto alloc = [&](size_t bytes) -> char* {
        char* r = base + off;
        off = (off + bytes + 255) & ~(size_t)255;
        return r;
    };

    const bool fullM = ws_size >= (size_t)236 * 1024 * 1024;
    const long long MC = fullM ? M : M / 2;

    float* part = (float*)alloc(4096 * 4);
    float* scales = (float*)alloc(256);
    float* dqx = (float*)alloc((size_t)M * 4);
    float* dqh = (float*)alloc((size_t)M * 4);
    signed char* wq = (signed char*)alloc((size_t)H * D);      // w1 then w2 overlay
    signed char* xq = (signed char*)alloc((size_t)M * D);
    signed char* hq = (signed char*)alloc((size_t)M * H);      // int8 h (full)
    unsigned short* hf = (unsigned short*)alloc((size_t)MC * H * 2);  // fp16 h

    const int nw4 = H * D / 4;
    abssum2<<<4096, TPB, 0, stream>>>(w1, w2, nw4, part);
    finalize_scales<<<1, TPB, 0, stream>>>(part, scales, 1.0f / (float)(H * D));
    quant_w_i8<<<2048, TPB, 0, stream>>>(w1, wq, scales, 0, nw4);
    quant_x_i8<2><<<(int)M, TPB, 0, stream>>>(x, xq, dqx, D);

    if (fullM) {
        gemm1p<<<dim3(32, 8), 512, 0, stream>>>(xq, wq, hf, H, D, dqx, scales, 4);
        quant_h_i8<4><<<(int)M, TPB, 0, stream>>>(hf, hq, dqh, H);
    } else {
        for (int g = 0; g < 2; ++g) {
            const long long m0 = g * MC;
            gemm1p<<<dim3(32, 8), 512, 0, stream>>>(
                xq + m0 * D, wq, hf, H, D, dqx + m0, scales, 2);
            quant_h_i8<4><<<(int)MC, TPB, 0, stream>>>(hf, hq + m0 * H, dqh + m0, H);
        }
    }

    quant_w_i8<<<2048, TPB, 0, stream>>>(w2, wq, scales, 1, nw4);

    gemm2k<<<dim3(D / 256, (int)(M / 256)), 512, 0, stream>>>(
        hq, wq, out, D, H, dqh, scales);
}

// Round 14
// 349.433 us; speedup vs baseline: 1.2338x; 1.0237x over previous
//
#include <hip/hip_runtime.h>
#include <hip/hip_bf16.h>
#include <hip/hip_fp16.h>
#include <stdint.h>

#define TPB 256
#define EPSF 1e-5f

using i32x4 = __attribute__((ext_vector_type(4))) int;

// ---------------- helpers ----------------

__device__ __forceinline__ void gload16(const void* g, void* l) {
    __builtin_amdgcn_global_load_lds(
        (__attribute__((address_space(1))) void*)g,
        (__attribute__((address_space(3))) void*)l,
        16, 0, 0);
}

__device__ __forceinline__ float wave_reduce_sum(float v) {
#pragma unroll
    for (int off = 32; off > 0; off >>= 1) v += __shfl_down(v, off, 64);
    return v;
}

__device__ __forceinline__ float wave_reduce_max(float v) {
#pragma unroll
    for (int off = 32; off > 0; off >>= 1) v = fmaxf(v, __shfl_down(v, off, 64));
    return v;
}

__device__ __forceinline__ int q8(float f, float scale, float lo, float hi) {
    return (int)fminf(fmaxf(rintf(f * scale), lo), hi);
}

// fast GELU: x * sigmoid(2*u), u = sqrt(2/pi)*(x + 0.044715 x^3)
__device__ __forceinline__ float gelu_fast(float x) {
    float x2 = x * x;
    float u = x * (0.7978845608f + 0.0356774081f * x2);
    float e = exp2f(u * -2.8853900817779268f);   // exp(-2u)
    return x * __builtin_amdgcn_rcpf(1.0f + e);
}

// ---------------- scale reduction (deterministic two-pass) ----------------

__global__ void abssum2(const float* __restrict__ w1, const float* __restrict__ w2,
                        int n4, float* __restrict__ part) {
    const bool second = blockIdx.x >= 2048;
    const float4* w4 = (const float4*)(second ? w2 : w1);
    const int b = blockIdx.x & 2047;
    float acc = 0.f;
    for (int i = b * TPB + threadIdx.x; i < n4; i += 2048 * TPB) {
        float4 v = w4[i];
        acc += fabsf(v.x) + fabsf(v.y) + fabsf(v.z) + fabsf(v.w);
    }
    acc = wave_reduce_sum(acc);
    __shared__ float sh[4];
    if ((threadIdx.x & 63) == 0) sh[threadIdx.x >> 6] = acc;
    __syncthreads();
    if (threadIdx.x == 0) part[blockIdx.x] = sh[0] + sh[1] + sh[2] + sh[3];
}

__global__ void finalize_scales(const float* __restrict__ part,
                                float* __restrict__ scales, float inv_n) {
    float a = 0.f, b = 0.f;
    for (int i = threadIdx.x; i < 2048; i += TPB) { a += part[i]; b += part[i + 2048]; }
    a = wave_reduce_sum(a);
    b = wave_reduce_sum(b);
    __shared__ float sa[4], sb[4];
    if ((threadIdx.x & 63) == 0) { sa[threadIdx.x >> 6] = a; sb[threadIdx.x >> 6] = b; }
    __syncthreads();
    if (threadIdx.x == 0) {
        scales[0] = fmaxf((sa[0] + sa[1] + sa[2] + sa[3]) * inv_n, EPSF);
        scales[1] = fmaxf((sb[0] + sb[1] + sb[2] + sb[3]) * inv_n, EPSF);
    }
}

// ---------------- weight ternarization -> int8 (natural K order, for w1) -----

__global__ void quant_w_i8(const float* __restrict__ w,
                           signed char* __restrict__ wq,
                           const float* __restrict__ scales, int sidx, int n4) {
    const float inv = 1.0f / scales[sidx];
    const float4* w4 = (const float4*)w;
    unsigned* oq = (unsigned*)wq;
    for (int i = blockIdx.x * TPB + threadIdx.x; i < n4; i += gridDim.x * TPB) {
        float4 v = w4[i];
        unsigned p = ((unsigned)(q8(v.x, inv, -1.f, 1.f) & 0xff)) |
                     ((unsigned)(q8(v.y, inv, -1.f, 1.f) & 0xff) << 8) |
                     ((unsigned)(q8(v.z, inv, -1.f, 1.f) & 0xff) << 16) |
                     ((unsigned)(q8(v.w, inv, -1.f, 1.f) & 0xff) << 24);
        oq[i] = p;
    }
}

// ---------------- w2 ternarization with within-64 K-permutation -------------
// pi(c) = 4*(c&15) + ((c>>4)&3) within each 64-aligned K group. h/hq use the
// same pi, so GEMM2's MFMA pairs identical logical k in matching byte slots.
// Gather via 16-lane shuffle: output dword g's byte j = element c=16j+g of the
// group, owned by lane (base + 4j + (g>>2)) byte (g&3). Reads/writes coalesced.

__global__ void quant_w2_i8perm(const float* __restrict__ w,
                                signed char* __restrict__ wq,
                                const float* __restrict__ scales, int n4) {
    const float inv = 1.0f / scales[1];
    const float4* w4 = (const float4*)w;
    unsigned* oq = (unsigned*)wq;
    const int t = threadIdx.x;
    const int g = t & 15;
    const int srcbase = (t & ~15);
    for (int i = blockIdx.x * TPB + t; i < n4; i += gridDim.x * TPB) {
        float4 v = w4[i];
        unsigned p = ((unsigned)(q8(v.x, inv, -1.f, 1.f) & 0xff)) |
                     ((unsigned)(q8(v.y, inv, -1.f, 1.f) & 0xff) << 8) |
                     ((unsigned)(q8(v.z, inv, -1.f, 1.f) & 0xff) << 16) |
                     ((unsigned)(q8(v.w, inv, -1.f, 1.f) & 0xff) << 24);
        unsigned out = 0;
#pragma unroll
        for (int j = 0; j < 4; ++j) {
            unsigned pj = (unsigned)__shfl((int)p, srcbase + 4 * j + (g >> 2), 64);
            out |= ((pj >> ((g & 3) * 8)) & 0xffu) << (8 * j);
        }
        oq[i] = out;
    }
}

// ---------------- per-row activation quant: fp32 -> int8 ----------------

template <int NF4>
__global__ void quant_x_i8(const float* __restrict__ in,
                           signed char* __restrict__ outq,
                           float* __restrict__ dq, int cols) {
    const long long row = blockIdx.x;
    const float4* r4 = (const float4*)(in + row * (long long)cols);
    float4 v[NF4];
    float mx = 0.f;
#pragma unroll
    for (int j = 0; j < NF4; ++j) {
        v[j] = r4[threadIdx.x + TPB * j];
        mx = fmaxf(mx, fmaxf(fmaxf(fabsf(v[j].x), fabsf(v[j].y)),
                             fmaxf(fabsf(v[j].z), fabsf(v[j].w))));
    }
    mx = wave_reduce_max(mx);
    __shared__ float sh[4];
    __shared__ float res;
    if ((threadIdx.x & 63) == 0) sh[threadIdx.x >> 6] = mx;
    __syncthreads();
    if (threadIdx.x == 0) res = fmaxf(fmaxf(sh[0], sh[1]), fmaxf(sh[2], sh[3]));
    __syncthreads();
    const float clipped = fmaxf(res, EPSF);
    const float scale = 127.f / clipped;
    if (threadIdx.x == 0) dq[row] = clipped / 127.f;
    unsigned* oq = (unsigned*)(outq + row * (long long)cols);
#pragma unroll
    for (int j = 0; j < NF4; ++j) {
        unsigned p = ((unsigned)(q8(v[j].x, scale, -128.f, 127.f) & 0xff)) |
                     ((unsigned)(q8(v[j].y, scale, -128.f, 127.f) & 0xff) << 8) |
                     ((unsigned)(q8(v[j].z, scale, -128.f, 127.f) & 0xff) << 16) |
                     ((unsigned)(q8(v[j].w, scale, -128.f, 127.f) & 0xff) << 24);
        oq[threadIdx.x + TPB * j] = p;
    }
}

// ---------------- per-row quant: fp16 (pre-gelu) -> gelu -> int8 ------------
// gelu moved here from the GEMM1 epilogue: this kernel is BW-bound with idle
// VALU. Positions preserved (permuted layout flows through to hq).

template <int NJ>
__global__ void quant_h_i8(const unsigned short* __restrict__ h,
                           signed char* __restrict__ outq,
                           float* __restrict__ dq, int cols) {
    const long long row = blockIdx.x;
    const unsigned short* rp = h + row * (long long)cols;
    float g[NJ * 8];
    float mx = 0.f;
#pragma unroll
    for (int j = 0; j < NJ; ++j) {
        uint4 v = *(const uint4*)(rp + (threadIdx.x + TPB * j) * 8);
        const unsigned* u = (const unsigned*)&v;
#pragma unroll
        for (int e = 0; e < 4; ++e) {
            float2 f2 = __half22float2(*(const __half2*)&u[e]);
            float g0 = gelu_fast(f2.x);
            float g1 = gelu_fast(f2.y);
            g[j * 8 + 2 * e] = g0;
            g[j * 8 + 2 * e + 1] = g1;
            mx = fmaxf(mx, fmaxf(fabsf(g0), fabsf(g1)));
        }
    }
    mx = wave_reduce_max(mx);
    __shared__ float sh[4];
    __shared__ float res;
    if ((threadIdx.x & 63) == 0) sh[threadIdx.x >> 6] = mx;
    __syncthreads();
    if (threadIdx.x == 0) res = fmaxf(fmaxf(sh[0], sh[1]), fmaxf(sh[2], sh[3]));
    __syncthreads();
    const float clipped = fmaxf(res, EPSF);
    const float scale = 127.f / clipped;
    if (threadIdx.x == 0) dq[row] = clipped / 127.f;
    uint2* oq = (uint2*)(outq + row * (long long)cols);
#pragma unroll
    for (int j = 0; j < NJ; ++j) {
        unsigned o[2] = {0, 0};
#pragma unroll
        for (int e = 0; e < 8; ++e) {
            unsigned b = (unsigned)(q8(g[j * 8 + e], scale, -128.f, 127.f) & 0xff);
            o[e >> 2] |= b << ((e & 3) * 8);
        }
        oq[threadIdx.x + TPB * j] = *(uint2*)o;
    }
}

// ---------------- shared GEMM pieces ----------------

__device__ __forceinline__ void stage_half(const char* Xb, long long rowB, int prow,
                                           int tk, char* dst, int tid, int cbs) {
    const long long gc = (long long)tk * 128 + cbs;
    const int r = tid >> 3;
    gload16(Xb + (long long)(prow + r) * rowB + gc, dst + tid * 16);
    gload16(Xb + (long long)(prow + 64 + r) * rowB + gc, dst + 8192 + tid * 16);
}

#define QUAD(MB, NB)                                                            \
    _Pragma("unroll") for (int mi = 0; mi < 4; ++mi)                            \
    _Pragma("unroll") for (int ni = 0; ni < 2; ++ni)                            \
    _Pragma("unroll") for (int ks = 0; ks < 2; ++ks)                            \
        acc[(MB)*4 + mi][(NB)*2 + ni] = __builtin_amdgcn_mfma_i32_16x16x64_i8(  \
            aq[mi][ks], bq[(NB)*2 + ni][ks], acc[(MB)*4 + mi][(NB)*2 + ni], 0, 0, 0);

#define READ_A(BUF, base_mi)                                                    \
    _Pragma("unroll") for (int mi = 0; mi < 4; ++mi) {                          \
        const char* p = (BUF) + aoff + ((mi + (base_mi)) * 16 + l15) * 128;     \
        aq[mi][0] = *(const i32x4*)(p + acb0);                                  \
        aq[mi][1] = *(const i32x4*)(p + acb1);                                  \
    }
#define READ_B(BUF, n0i, n1i)                                                   \
    _Pragma("unroll") for (int ni = (n0i); ni < (n1i); ++ni) {                  \
        const char* p = (BUF) + boff + (ni * 16 + l15) * 128;                   \
        bq[ni][0] = *(const i32x4*)(p + acb0);                                  \
        bq[ni][1] = *(const i32x4*)(p + acb1);                                  \
    }

#define LGKM(N) do { asm volatile("s_waitcnt lgkmcnt(" #N ")" ::: "memory");    \
                     __builtin_amdgcn_sched_barrier(0); } while (0)

// split epilogue for gemm1p: rows [MLO,MHI), NO gelu (moved to quant_h),
// pi-packed 8B stores: element col' = n0 + wc*64 + l15*4 + ni  (pi layout)
#define EMIT1(MLO, MHI, M0V)                                                    \
    _Pragma("unroll") for (int mi = (MLO); mi < (MHI); ++mi) {                  \
        _Pragma("unroll") for (int r = 0; r < 4; ++r) {                         \
            const long long m = (M0V) + wr * 128 + mi * 16 + l4 * 4 + r;        \
            const float f = dq[m] * s;                                          \
            __half2 lo = __floats2half2_rn((float)acc[mi][0][r] * f,            \
                                           (float)acc[mi][1][r] * f);           \
            __half2 hi = __floats2half2_rn((float)acc[mi][2][r] * f,            \
                                           (float)acc[mi][3][r] * f);           \
            uint2 pk;                                                           \
            pk.x = *(const unsigned*)&lo;                                       \
            pk.y = *(const unsigned*)&hi;                                       \
            *(uint2*)(C + m * (long long)N + n0 + wc * 64 + l15 * 4) = pk;      \
            acc[mi][0][r] = 0; acc[mi][1][r] = 0;                               \
            acc[mi][2][r] = 0; acc[mi][3][r] = 0;                               \
        }                                                                       \
    }

// ---------------- persistent GEMM1: x@w1^T -> fp16 h' (pi layout) -----------
// R9 read-ahead skeleton, unchanged schedule; thin epilogue.

__global__ __launch_bounds__(512, 2) void gemm1p(
    const signed char* __restrict__ A, const signed char* __restrict__ B,
    unsigned short* __restrict__ C, int N, int K,
    const float* __restrict__ dq, const float* __restrict__ scales, int ntile) {
    __shared__ __align__(16) char lds[131072];

    const int tid = threadIdx.x;
    const int lane = tid & 63;
    const int wid = tid >> 6;
    const int wr = wid >> 2;
    const int wc = wid & 3;

    const unsigned orig = blockIdx.y * gridDim.x + blockIdx.x;
    const unsigned xk = orig & 7, j = orig >> 3;
    const unsigned bx = xk * 4 + (j & 3);      // N band 0..31 (4 per XCD)
    const unsigned byg = j >> 2;               // M group 0..7

    const int n0 = (int)bx * 256;
    const long long rb = (long long)K;
    const char* Ab = (const char*)A;
    const char* Bb = (const char*)B;

    const int NTT = ntile << 4;

    const int cbs = (((tid & 7) ^ ((tid >> 3) & 7)) << 4);
    const int l15 = lane & 15, l4 = lane >> 4;
    const int swz = (lane & 7) << 4;
    const int acb0 = (l4 * 16) ^ swz;
    const int acb1 = (64 + l4 * 16) ^ swz;
    const int aoff = wr * 16384;
    const int boff = 32768 + (wc >> 1) * 16384 + (wc & 1) * 8192;

    i32x4 acc[8][4] = {};
    i32x4 aq[4][2], bq[4][2];

    auto mrow = [&](int v) -> int { return ((int)byg * ntile + (v >> 4)) * 256; };

    stage_half(Bb, rb, n0, 0, lds + 32768, tid, cbs);
    stage_half(Bb, rb, n0 + 128, 0, lds + 32768 + 16384, tid, cbs);
    stage_half(Ab, rb, mrow(0), 0, lds + 0, tid, cbs);
    stage_half(Ab, rb, mrow(0) + 128, 0, lds + 16384, tid, cbs);
    stage_half(Bb, rb, n0, 1, lds + 65536 + 32768, tid, cbs);
    stage_half(Bb, rb, n0 + 128, 1, lds + 65536 + 32768 + 16384, tid, cbs);
    stage_half(Ab, rb, mrow(1), 1, lds + 65536, tid, cbs);
    asm volatile("s_waitcnt vmcnt(6)" ::: "memory");
    __builtin_amdgcn_sched_barrier(0);
    __builtin_amdgcn_s_barrier();
    READ_A(lds, 0);
    READ_B(lds, 0, 2);

    const float s = scales[0];

    for (int vt = 0; vt < NTT; ++vt) {
        char* cur = lds + ((vt & 1) << 16);
        char* nxt = lds + (((vt + 1) & 1) << 16);
        const bool s1 = (vt + 1) < NTT;
        const bool s2 = (vt + 2) < NTT;
        const int kk = vt & 15;
        const int k1 = (vt + 1) & 15;
        const int k2 = (vt + 2) & 15;

        // P0
        if (s1) stage_half(Ab, rb, mrow(vt + 1) + 128, k1, nxt + 16384, tid, cbs);
        READ_B(cur, 2, 4);
        if (kk == 0 && vt > 0) { EMIT1(4, 8, mrow(vt - 1)); }
        __builtin_amdgcn_s_barrier();
        LGKM(4);
        __builtin_amdgcn_s_setprio(1);
        QUAD(0, 0);
        __builtin_amdgcn_s_setprio(0);

        // P1
        __builtin_amdgcn_s_barrier();
        LGKM(0);
        __builtin_amdgcn_s_setprio(1);
        QUAD(0, 1);
        __builtin_amdgcn_s_setprio(0);

        // P2
        if (s2) {
            stage_half(Bb, rb, n0, k2, cur + 32768, tid, cbs);
            stage_half(Bb, rb, n0 + 128, k2, cur + 32768 + 16384, tid, cbs);
        }
        READ_A(cur, 4);
        if (kk == 15) { EMIT1(0, 4, mrow(vt)); }
        __builtin_amdgcn_s_barrier();
        LGKM(0);
        __builtin_amdgcn_s_setprio(1);
        QUAD(1, 0);
        __builtin_amdgcn_s_setprio(0);

        // P3
        if (s2) { asm volatile("s_waitcnt vmcnt(4)" ::: "memory"); }
        else    { asm volatile("s_waitcnt vmcnt(0)" ::: "memory"); }
        __builtin_amdgcn_sched_barrier(0);
        __builtin_amdgcn_s_barrier();
        if (s2) stage_half(Ab, rb, mrow(vt + 2), k2, cur, tid, cbs);
        __builtin_amdgcn_s_setprio(1);
        QUAD(1, 1);
        __builtin_amdgcn_s_setprio(0);
        if (s1) {
            READ_A(nxt, 0);
            READ_B(nxt, 0, 2);
        }
    }

    { EMIT1(4, 8, mrow(NTT - 1)); }
}

// ---------------- 256x256 read-ahead i8 GEMM2 (R9 exact) ----------------

#define EMIT2(MLO, MHI)                                                         \
    _Pragma("unroll") for (int mi = (MLO); mi < (MHI); ++mi) {                  \
        _Pragma("unroll") for (int r = 0; r < 4; ++r) {                         \
            const long long m = M0 + wr * 128 + mi * 16 + l4 * 4 + r;           \
            const float f = dq[m] * s;                                          \
            _Pragma("unroll") for (int ni = 0; ni < 4; ++ni) {                  \
                const long long n = N0 + wc * 64 + ni * 16 + l15;               \
                __builtin_nontemporal_store(                                    \
                    (float)acc[mi][ni][r] * f, C + m * (long long)N + n);       \
            }                                                                   \
        }                                                                       \
    }

__global__ __launch_bounds__(512, 2) void gemm2k(
    const signed char* __restrict__ A, const signed char* __restrict__ B,
    float* __restrict__ C, int N, int K,
    const float* __restrict__ dq, const float* __restrict__ scales) {
    __shared__ __align__(16) char lds[131072];

    const int tid = threadIdx.x;
    const int lane = tid & 63;
    const int wid = tid >> 6;
    const int wr = wid >> 2;
    const int wc = wid & 3;

    const unsigned gx = gridDim.x;
    unsigned lin = blockIdx.y * gx + blockIdx.x;
    const unsigned qq = (gx * gridDim.y) >> 3;
    lin = (lin & 7) * qq + (lin >> 3);
    const unsigned bx = lin % gx;
    const unsigned by = lin / gx;

    const long long M0 = (long long)by * 256;
    const long long N0 = (long long)bx * 256;
    const long long rb = (long long)K;
    const char* Ab = (const char*)A + M0 * rb;
    const char* Bb = (const char*)B + N0 * rb;
    const int nt = K >> 7;

    const int cbs = (((tid & 7) ^ ((tid >> 3) & 7)) << 4);
    const int l15 = lane & 15, l4 = lane >> 4;
    const int swz = (lane & 7) << 4;
    const int acb0 = (l4 * 16) ^ swz;
    const int acb1 = (64 + l4 * 16) ^ swz;
    const int aoff = wr * 16384;
    const int boff = 32768 + (wc >> 1) * 16384 + (wc & 1) * 8192;

    i32x4 acc[8][4] = {};
    i32x4 aq[4][2], bq[4][2];

    stage_half(Bb, rb, 0,   0, lds + 32768,         tid, cbs);
    stage_half(Bb, rb, 128, 0, lds + 32768 + 16384, tid, cbs);
    stage_half(Ab, rb, 0,   0, lds + 0,             tid, cbs);
    stage_half(Ab, rb, 128, 0, lds + 16384,         tid, cbs);
    stage_half(Bb, rb, 0,   1, lds + 65536 + 32768,         tid, cbs);
    stage_half(Bb, rb, 128, 1, lds + 65536 + 32768 + 16384, tid, cbs);
    stage_half(Ab, rb, 0,   1, lds + 65536,                 tid, cbs);
    asm volatile("s_waitcnt vmcnt(6)" ::: "memory");
    __builtin_amdgcn_sched_barrier(0);
    __builtin_amdgcn_s_barrier();
    READ_A(lds, 0);
    READ_B(lds, 0, 2);

    const float s = scales[1];

    for (int t = 0; t < nt; ++t) {
        char* cur = lds + ((t & 1) << 16);
        char* nxt = lds + (((t + 1) & 1) << 16);
        const bool s1 = (t + 1) < nt;
        const bool s2 = (t + 2) < nt;

        // P0
        if (s1) stage_half(Ab, rb, 128, t + 1, nxt + 16384, tid, cbs);
        READ_B(cur, 2, 4);
        __builtin_amdgcn_s_barrier();
        LGKM(4);
        __builtin_amdgcn_s_setprio(1);
        QUAD(0, 0);
        __builtin_amdgcn_s_setprio(0);

        // P1
        __builtin_amdgcn_s_barrier();
        LGKM(0);
        __builtin_amdgcn_s_setprio(1);
        QUAD(0, 1);
        __builtin_amdgcn_s_setprio(0);

        // P2
        if (s2) {
            stage_half(Bb, rb, 0, t + 2, cur + 32768, tid, cbs);
            stage_half(Bb, rb, 128, t + 2, cur + 32768 + 16384, tid, cbs);
        }
        READ_A(cur, 4);
        if (t == nt - 1) { EMIT2(0, 4); }
        __builtin_amdgcn_s_barrier();
        LGKM(0);
        __builtin_amdgcn_s_setprio(1);
        QUAD(1, 0);
        __builtin_amdgcn_s_setprio(0);

        // P3
        if (s2) { asm volatile("s_waitcnt vmcnt(4)" ::: "memory"); }
        else    { asm volatile("s_waitcnt vmcnt(0)" ::: "memory"); }
        __builtin_amdgcn_sched_barrier(0);
        __builtin_amdgcn_s_barrier();
        if (s2) stage_half(Ab, rb, 0, t + 2, cur, tid, cbs);
        __builtin_amdgcn_s_setprio(1);
        QUAD(1, 1);
        __builtin_amdgcn_s_setprio(0);
        if (s1) {
            READ_A(nxt, 0);
            READ_B(nxt, 0, 2);
        }
    }

    { EMIT2(4, 8); }
}

// ---------------- launcher ----------------

extern "C" void kernel_launch(void* const* d_in, const int* in_sizes, int n_in,
                              void* d_out, int out_size, void* d_ws, size_t ws_size,
                              hipStream_t stream) {
    (void)n_in; (void)out_size;
    const float* x  = (const float*)d_in[0];
    const float* w1 = (const float*)d_in[1];
    const float* w2 = (const float*)d_in[2];
    float* out = (float*)d_out;

    const int D = 2048, H = 8192;
    const long long M = (long long)in_sizes[0] / D;  // 8192

    char* base = (char*)d_ws;
    size_t off = 0;
    auto alloc = [&](size_t bytes) -> char* {
        char* r = base + off;
        off = (off + bytes + 255) & ~(size_t)255;
        return r;
    };

    const bool fullM = ws_size >= (size_t)236 * 1024 * 1024;
    const long long MC = fullM ? M : M / 2;

    float* part = (float*)alloc(4096 * 4);
    float* scales = (float*)alloc(256);
    float* dqx = (float*)alloc((size_t)M * 4);
    float* dqh = (float*)alloc((size_t)M * 4);
    signed char* wq = (signed char*)alloc((size_t)H * D);      // w1 then w2 overlay
    signed char* xq = (signed char*)alloc((size_t)M * D);
    signed char* hq = (signed char*)alloc((size_t)M * H);      // int8 h (pi layout)
    unsigned short* hf = (unsigned short*)alloc((size_t)MC * H * 2);  // fp16 h (pi)

    const int nw4 = H * D / 4;
    abssum2<<<4096, TPB, 0, stream>>>(w1, w2, nw4, part);
    finalize_scales<<<1, TPB, 0, stream>>>(part, scales, 1.0f / (float)(H * D));
    quant_w_i8<<<2048, TPB, 0, stream>>>(w1, wq, scales, 0, nw4);
    quant_x_i8<2><<<(int)M, TPB, 0, stream>>>(x, xq, dqx, D);

    if (fullM) {
        gemm1p<<<dim3(32, 8), 512, 0, stream>>>(xq, wq, hf, H, D, dqx, scales, 4);
        quant_h_i8<4><<<(int)M, TPB, 0, stream>>>(hf, hq, dqh, H);
    } else {
        for (int g = 0; g < 2; ++g) {
            const long long m0 = g * MC;
            gemm1p<<<dim3(32, 8), 512, 0, stream>>>(
                xq + m0 * D, wq, hf, H, D, dqx + m0, scales, 2);
            quant_h_i8<4><<<(int)MC, TPB, 0, stream>>>(hf, hq + m0 * H, dqh + m0, H);
        }
    }

    // w2 ternarized with the matching pi K-permutation
    quant_w2_i8perm<<<2048, TPB, 0, stream>>>(w2, wq, scales, nw4);

    gemm2k<<<dim3(D / 256, (int)(M / 256)), 512, 0, stream>>>(
        hq, wq, out, D, H, dqh, scales);
}